// Round 8
// baseline (732.427 us; speedup 1.0000x reference)
//
#include <hip/hip_runtime.h>
#include <hip/hip_bf16.h>

// ---------------------------------------------------------------------------
// SeparateTSQLinearNodeBlock: fused weighted symmetric TensorSquare (x2) +
// equivariant Linear, fp16 MFMA formulation.
//
//  out[n, 0:32]        = z0  = sum over paths (00, 11) x (feats, messages)
//  out[n, 32 + 3w + i] = z1  = path 01 x (feats, messages)
//
//  All CG/path/linear scales folded into precomputed f16 weights in d_ws:
//   V00sym : [2][32 wp][648 k]  (K=640 used; symmetric-folded, cell-pair enum)
//   V11sym : [2][32 wp][192 k]
//   V01t   : [2][256 row=(v*16+wp)][32 u]
//
//  R8 (R5 base = 535us + AGPR accumulators):
//   - acc0/acc1 FORCED into AGPRs via inline-asm "+a" MFMA (4 attribute
//     attempts never moved the 128-VGPR arch budget; "a" constraints extend
//     the allocation by construction). Arch-VGPR live state drops ~32 regs
//     -> spill traffic should vanish.
//   - manual hazard nops: s_nop 1 before each asm MFMA (VALU->MFMA srcA/B),
//     3x s_nop 7 before epilogue (MFMA->VALU read of AGPR).
//   - plain stores (R7: WRITE 697->605MB vs NT).
// ---------------------------------------------------------------------------

typedef __attribute__((ext_vector_type(8)))  _Float16 half8;
typedef __attribute__((ext_vector_type(2)))  _Float16 h16x2;
typedef __attribute__((ext_vector_type(16))) float    f32x16;
typedef __attribute__((ext_vector_type(4)))  float    f32x4;
typedef __attribute__((ext_vector_type(4)))  int      iv4;

#define V00_LDS_BYTES 82944              // 2*32*648*2
#define XBUF_BYTES    11264              // 704 chunks * 16B (32 rows * 84 f32 + pad)
#define SMEM_BYTES    (V00_LDS_BYTES + 7 * XBUF_BYTES)   // 161792 <= 163840
#define WS_V11_BYTE   82944
#define WS_V01_BYTE   107520
#define WAVE_STRIDE   1792               // 256 blocks * 7 waves

// ---- async global->LDS (16B per lane, linear dest = base + lane*16) --------
__device__ __forceinline__ void gll16(const void* g, void* l)
{
    __builtin_amdgcn_global_load_lds(
        (const __attribute__((address_space(1))) void*)g,
        (__attribute__((address_space(3))) void*)l,
        16, 0, 0);
}

#define WAIT_VM0()   asm volatile("s_waitcnt vmcnt(0)" ::: "memory")
#define WAIT_LGKM0() asm volatile("s_waitcnt lgkmcnt(0)" ::: "memory")

// ---- packed f16 helpers ----------------------------------------------------
__device__ __forceinline__ unsigned pkrtz(float a, float b)
{
    auto h = __builtin_amdgcn_cvt_pkrtz(a, b);    // __fp16 ext_vector(2)
    unsigned u;
    __builtin_memcpy(&u, &h, 4);
    return u;
}
__device__ __forceinline__ unsigned pkmul(unsigned a, unsigned b)
{
    h16x2 r = __builtin_bit_cast(h16x2, a) * __builtin_bit_cast(h16x2, b);
    return __builtin_bit_cast(unsigned, r);
}
__device__ __forceinline__ unsigned pkfma(unsigned a, unsigned b, unsigned c)
{
    h16x2 r = __builtin_bit_cast(h16x2, a) * __builtin_bit_cast(h16x2, b)
            + __builtin_bit_cast(h16x2, c);       // -ffp-contract fuses
    return __builtin_bit_cast(unsigned, r);
}
// select low/high half per h1 and splat into both halves
__device__ __forceinline__ unsigned splat_sel(unsigned pair, int h1)
{
    unsigned v = h1 ? (pair >> 16) : (pair & 0xffffu);
    return v | (v << 16);
}
__device__ __forceinline__ float lo_f(unsigned p)
{
    return (float)__builtin_bit_cast(h16x2, p)[0];
}
__device__ __forceinline__ float hi_f(unsigned p)
{
    return (float)__builtin_bit_cast(h16x2, p)[1];
}

// MFMA with accumulator pinned in AGPRs. s_nop 1 covers the VALU-write ->
// MFMA-read srcA/B hazard (hazard recognizer can't see into inline asm).
__device__ __forceinline__ void mfma_agpr(f32x16& acc, iv4 a, iv4 b)
{
    asm("s_nop 1\n\tv_mfma_f32_32x32x16_f16 %0, %1, %2, %0"
        : "+a"(acc) : "v"(a), "v"(b));
}

__device__ __forceinline__ f32x16 mfma_f16(iv4 a, iv4 b, f32x16 c)
{
    return __builtin_amdgcn_mfma_f32_32x32x16_f16(
        __builtin_bit_cast(half8, a), __builtin_bit_cast(half8, b), c, 0, 0, 0);
}

// ---- symmetric-pair cell enumeration (shared by prep + main) ---------------
// K-step kk -> (v-run r, base row u0); slot k = kk*16 + 8*h + j maps to the
// pair (u = u0 + h, v = 8*r + j); slots with v < u carry zero weight (pad).
__device__ __forceinline__ void dec00(int kk, int& r, int& u0)
{
    if      (kk < 4)  { r = 0; u0 = kk * 2; }
    else if (kk < 12) { r = 1; u0 = (kk - 4) * 2; }
    else if (kk < 24) { r = 2; u0 = (kk - 12) * 2; }
    else              { r = 3; u0 = (kk - 24) * 2; }
}
__device__ __forceinline__ void dec11(int kk, int& r, int& u0)
{
    if (kk < 4) { r = 0; u0 = kk * 2; }
    else        { r = 1; u0 = (kk - 4) * 2; }
}

// ---------------------------------------------------------------------------
// Precompute kernel: fold L0/L1 + path scales + symmetry into f16 weights.
// One thread per output element (70,144 total).
// ---------------------------------------------------------------------------
__global__ void prep_weights(const float* __restrict__ W00_1, const float* __restrict__ W01_1,
                             const float* __restrict__ W11_1, const float* __restrict__ W00_2,
                             const float* __restrict__ W01_2, const float* __restrict__ W11_2,
                             const float* __restrict__ L0,    const float* __restrict__ L1,
                             _Float16* __restrict__ ws)
{
    int t = blockIdx.x * 256 + threadIdx.x;
    const float s00 = 1.0f / (32.0f * sqrtf(32.0f));
    const float s11 = 0.57735026919f / (16.0f * sqrtf(32.0f));
    const float s01 = 1.0f / sqrtf(8192.0f);

    if (t < 2 * 32 * 648) {                       // V00sym
        int k  = t % 648;
        int rw = t / 648;
        int wp = rw & 31, s = rw >> 5;
        const float* W = s ? W00_2 : W00_1;
        float val = 0.f;
        int kk = k >> 4;
        if (kk < 40) {
            int h = (k >> 3) & 1, j = k & 7, r, u0;
            dec00(kk, r, u0);
            int u = u0 + h, v = 8 * r + j;
            if (v >= u) {
                float acc = 0.f;
                for (int w = 0; w < 32; ++w) {
                    float c = W[(u * 32 + v) * 32 + w];
                    if (u != v) c += W[(v * 32 + u) * 32 + w];
                    acc += c * L0[w * 32 + wp];
                }
                val = acc * s00;
            }
        }
        ws[t] = (_Float16)val;
        return;
    }
    t -= 2 * 32 * 648;
    if (t < 2 * 32 * 192) {                       // V11sym
        int k  = t % 192;
        int rw = t / 192;
        int wp = rw & 31, s = rw >> 5;
        const float* W = s ? W11_2 : W11_1;
        int kk = k >> 4, h = (k >> 3) & 1, j = k & 7, r, u0;
        dec11(kk, r, u0);
        int u = u0 + h, v = 8 * r + j;
        float val = 0.f;
        if (v >= u) {
            float acc = 0.f;
            for (int w = 0; w < 32; ++w) {
                float c = W[(u * 16 + v) * 32 + w];
                if (u != v) c += W[(v * 16 + u) * 32 + w];
                acc += c * L0[w * 32 + wp];
            }
            val = acc * s11;
        }
        ws[2 * 32 * 648 + t] = (_Float16)val;
        return;
    }
    t -= 2 * 32 * 192;
    if (t < 2 * 256 * 32) {                       // V01 (transposed, L1-folded)
        int u  = t & 31;
        int rw = t >> 5;
        int row = rw & 255, s = rw >> 8;
        int v = row >> 4, wp = row & 15;
        const float* W = s ? W01_2 : W01_1;
        float acc = 0.f;
        for (int w = 0; w < 16; ++w)
            acc += W[(u * 16 + v) * 16 + w] * L1[w * 16 + wp];
        ws[2 * 32 * 648 + 2 * 32 * 192 + t] = (_Float16)(acc * s01);
    }
}

// ---------------------------------------------------------------------------
// Stage one 32-node tile (80 f32/row) into LDS rows of stride 84 f32 (336B).
// 11 global_load_lds x 1KB; LDS dest linear, src index derived per lane.
// ---------------------------------------------------------------------------
__device__ __forceinline__ void stage32(const float* __restrict__ src, char* xbuf, int lane)
{
#pragma unroll
    for (int st = 0; st < 11; ++st) {
        int q  = st * 64 + lane;
        int r  = q / 21;
        int cc = q - r * 21;
        if (r > 31) { r = 31; cc = 20; }
        int col = cc * 4;
        if (col > 76) col = 76;                    // pad chunk -> dup last 16B
        gll16(src + r * 80 + col, xbuf + st * 1024);
    }
}

// ---------------------------------------------------------------------------
// Main kernel: 7 waves/block, 1 block/CU, each wave owns a 32-node tile loop.
// Accumulators live in AGPRs (forced); arch VGPRs hold only VALU state.
// ---------------------------------------------------------------------------
__global__ __launch_bounds__(448)
void tsq_main(const float* __restrict__ xf, const float* __restrict__ xm,
              const unsigned short* __restrict__ wsb, float* __restrict__ out,
              int ntiles)
{
    __shared__ __align__(16) char smem[SMEM_BYTES];
    const int lane = threadIdx.x & 63;
    const int wid  = (int)(threadIdx.x >> 6);
    const int h1   = lane >> 5;                    // lane-half
    const int wp   = lane & 31;
    char* xbuf = smem + V00_LDS_BYTES + wid * XBUF_BYTES;

    // ---- cooperative V00 load to LDS (81 KB-chunks) ----
    for (int c = wid; c < 81; c += 7)
        gll16((const char*)wsb + c * 1024 + lane * 16, smem + c * 1024);
    WAIT_VM0();
    __syncthreads();

    const int wg = blockIdx.x * 7 + wid;
    if (wg < ntiles)
        stage32(xf + (size_t)wg * 2560, xbuf, lane);

    for (int t = wg; t < ntiles; t += WAVE_STRIDE) {
        const int tn = t + WAVE_STRIDE;

        f32x16 acc0, acc1;
#pragma unroll
        for (int e = 0; e < 16; ++e) { acc0[e] = 0.f; acc1[e] = 0.f; }
        // pin both accumulators into the AGPR file for their whole lifetime
        asm("" : "+a"(acc0), "+a"(acc1));

        float z1a[8][3];
#pragma unroll
        for (int d = 0; d < 8; ++d) { z1a[d][0] = 0.f; z1a[d][1] = 0.f; z1a[d][2] = 0.f; }

#pragma unroll 1
        for (int s = 0; s < 2; ++s) {
            // staged x ready
            WAIT_VM0();

            // ---- read my node row, convert to packed f16 pairs ----
            // xh0[q]    = (x0[2q], x0[2q+1])
            // xh1[i][p] = (x1[2p][i], x1[2p+1][i])
            unsigned xh0[16], xh1[3][8];
            const char* myrow = xbuf + wp * 336;
#pragma unroll
            for (int k = 0; k < 8; ++k) {
                float4 v = *reinterpret_cast<const float4*>(myrow + k * 16);
                xh0[2 * k + 0] = pkrtz(v.x, v.y);
                xh0[2 * k + 1] = pkrtz(v.z, v.w);
            }
            // x1: rows v at float offset v*3+i; process 4 v-rows (2 pairs)
            // per step from 3 float4s -> 12-float transient
#pragma unroll
            for (int pp = 0; pp < 4; ++pp) {
                float4 a = *reinterpret_cast<const float4*>(myrow + 128 + pp * 48);
                float4 b = *reinterpret_cast<const float4*>(myrow + 128 + pp * 48 + 16);
                float4 c = *reinterpret_cast<const float4*>(myrow + 128 + pp * 48 + 32);
                xh1[0][2 * pp + 0] = pkrtz(a.x, a.w);   // rows 4pp,4pp+1  i=0
                xh1[1][2 * pp + 0] = pkrtz(a.y, b.x);   //                 i=1
                xh1[2][2 * pp + 0] = pkrtz(a.z, b.y);   //                 i=2
                xh1[0][2 * pp + 1] = pkrtz(b.z, c.y);   // rows 4pp+2,4pp+3
                xh1[1][2 * pp + 1] = pkrtz(b.w, c.z);
                xh1[2][2 * pp + 1] = pkrtz(c.x, c.w);
            }
            WAIT_LGKM0();                          // buffer reusable

            // ---- overlap: stage next piece while computing this one ----
            if (s == 0)            stage32(xm + (size_t)t  * 2560, xbuf, lane);
            else if (tn < ntiles)  stage32(xf + (size_t)tn * 2560, xbuf, lane);

            // ---- path 00 : z0 += V00sym x P00 (K=640) ----
            // even kk -> acc0, odd kk -> acc1: two independent MFMA chains
            const char* v00b = smem + s * 41472 + wp * 1296 + h1 * 16;
#pragma unroll
            for (int kk = 0; kk < 40; ++kk) {
                int rr, u0; dec00(kk, rr, u0);
                unsigned ub = splat_sel(xh0[u0 >> 1], h1);   // CSE across kk
                iv4 bf;
#pragma unroll
                for (int q = 0; q < 4; ++q)
                    bf[q] = (int)pkmul(ub, xh0[4 * rr + q]);
                iv4 af = *reinterpret_cast<const iv4*>(v00b + kk * 32);
                if (kk & 1) mfma_agpr(acc1, af, bf);
                else        mfma_agpr(acc0, af, bf);
            }

            // ---- path 11 : z0 += V11sym x D11 (K=192), weights from L2 ----
            const char* v11g = (const char*)wsb + WS_V11_BYTE
                             + (size_t)((s * 32 + wp) * 192) * 2 + h1 * 16;
#pragma unroll
            for (int kk = 0; kk < 12; ++kk) {
                int rr, u0; dec11(kk, rr, u0);
                int q0 = u0 >> 1;
                unsigned b0 = splat_sel(xh1[0][q0], h1);
                unsigned b1 = splat_sel(xh1[1][q0], h1);
                unsigned b2 = splat_sel(xh1[2][q0], h1);
                iv4 bf;
#pragma unroll
                for (int q = 0; q < 4; ++q) {
                    int vp = 4 * rr + q;
                    unsigned d = pkmul(b0, xh1[0][vp]);
                    d = pkfma(b1, xh1[1][vp], d);
                    d = pkfma(b2, xh1[2][vp], d);
                    bf[q] = (int)d;
                }
                iv4 af = *reinterpret_cast<const iv4*>(v11g + kk * 32);
                if (kk & 1) mfma_agpr(acc1, af, bf);
                else        mfma_agpr(acc0, af, bf);
            }

            // ---- path 01 : t = V01t x x0 (K=32), then VALU contract over v ----
            iv4 b01[2];
#pragma unroll
            for (int kk = 0; kk < 2; ++kk)
#pragma unroll
                for (int q = 0; q < 4; ++q)
                    b01[kk][q] = (int)xh0[kk * 8 + 4 * h1 + q];

            const char* v01g = (const char*)wsb + WS_V01_BYTE
                             + (size_t)((s * 256 + wp) * 32) * 2 + h1 * 16;
#pragma unroll
            for (int m = 0; m < 8; ++m) {
                iv4 a0 = *reinterpret_cast<const iv4*>(v01g + m * 2048);
                iv4 a1 = *reinterpret_cast<const iv4*>(v01g + m * 2048 + 32);
                f32x16 tq;
#pragma unroll
                for (int e = 0; e < 16; ++e) tq[e] = 0.f;
                tq = mfma_f16(a0, b01[0], tq);
                tq = mfma_f16(a1, b01[1], tq);
                float x1f[2][3];
#pragma unroll
                for (int i = 0; i < 3; ++i) {
                    unsigned p = xh1[i][m];
                    x1f[0][i] = lo_f(p);           // v = 2m
                    x1f[1][i] = hi_f(p);           // v = 2m+1
                }
#pragma unroll
                for (int reg = 0; reg < 16; ++reg) {
                    int vloc = reg >> 3;
                    int d    = (reg & 3) + 4 * ((reg >> 2) & 1);
                    z1a[d][0] = fmaf(tq[reg], x1f[vloc][0], z1a[d][0]);
                    z1a[d][1] = fmaf(tq[reg], x1f[vloc][1], z1a[d][1]);
                    z1a[d][2] = fmaf(tq[reg], x1f[vloc][2], z1a[d][2]);
                }
            }
        } // set loop

        // MFMA(AGPR write) -> VALU/accvgpr_read hazard cover
        asm volatile("s_nop 7\n\ts_nop 7\n\ts_nop 7" ::);

        // ---- epilogue: this lane owns node (t*32 + wp), half-split outputs ----
        float* orow = out + (size_t)(t * 32 + wp) * 80;
#pragma unroll
        for (int qn = 0; qn < 4; ++qn) {
            f32x4 vz = { acc0[4 * qn + 0] + acc1[4 * qn + 0],
                         acc0[4 * qn + 1] + acc1[4 * qn + 1],
                         acc0[4 * qn + 2] + acc1[4 * qn + 2],
                         acc0[4 * qn + 3] + acc1[4 * qn + 3] };
            *reinterpret_cast<f32x4*>(orow + 8 * qn + 4 * h1) = vz;
        }
        float* p1 = orow + 32 + 12 * h1;
        {
            f32x4 a = { z1a[0][0], z1a[0][1], z1a[0][2], z1a[1][0] };
            f32x4 b = { z1a[1][1], z1a[1][2], z1a[2][0], z1a[2][1] };
            f32x4 c = { z1a[2][2], z1a[3][0], z1a[3][1], z1a[3][2] };
            *reinterpret_cast<f32x4*>(p1 + 0) = a;
            *reinterpret_cast<f32x4*>(p1 + 4) = b;
            *reinterpret_cast<f32x4*>(p1 + 8) = c;
        }
        float* p2 = orow + 56 + 12 * h1;
        {
            f32x4 a = { z1a[4][0], z1a[4][1], z1a[4][2], z1a[5][0] };
            f32x4 b = { z1a[5][1], z1a[5][2], z1a[6][0], z1a[6][1] };
            f32x4 c = { z1a[6][2], z1a[7][0], z1a[7][1], z1a[7][2] };
            *reinterpret_cast<f32x4*>(p2 + 0) = a;
            *reinterpret_cast<f32x4*>(p2 + 4) = b;
            *reinterpret_cast<f32x4*>(p2 + 8) = c;
        }
    }
}

// ---------------------------------------------------------------------------
extern "C" void kernel_launch(void* const* d_in, const int* in_sizes, int n_in,
                              void* d_out, int out_size, void* d_ws, size_t ws_size,
                              hipStream_t stream)
{
    const float* xf    = (const float*)d_in[0];
    const float* xm    = (const float*)d_in[1];
    const float* W00_1 = (const float*)d_in[2];
    const float* W01_1 = (const float*)d_in[3];
    const float* W11_1 = (const float*)d_in[4];
    const float* W00_2 = (const float*)d_in[5];
    const float* W01_2 = (const float*)d_in[6];
    const float* W11_2 = (const float*)d_in[7];
    const float* L0    = (const float*)d_in[8];
    const float* L1    = (const float*)d_in[9];

    const int N      = in_sizes[0] / 80;           // 1,000,000
    const int ntiles = N / 32;                     // 31,250 (exact)

    prep_weights<<<274, 256, 0, stream>>>(W00_1, W01_1, W11_1,
                                          W00_2, W01_2, W11_2,
                                          L0, L1, (_Float16*)d_ws);

    tsq_main<<<256, 448, 0, stream>>>(xf, xm,
                                      (const unsigned short*)d_ws,
                                      (float*)d_out, ntiles);
}

// Round 9
// 520.250 us; speedup vs baseline: 1.4078x; 1.4078x over previous
//
#include <hip/hip_runtime.h>
#include <hip/hip_bf16.h>

// ---------------------------------------------------------------------------
// SeparateTSQLinearNodeBlock: fused weighted symmetric TensorSquare (x2) +
// equivariant Linear, fp16 MFMA formulation.
//
//  out[n, 0:32]        = z0  = sum over paths (00, 11) x (feats, messages)
//  out[n, 32 + 3w + i] = z1  = path 01 x (feats, messages)
//
//  All CG/path/linear scales folded into precomputed f16 weights in d_ws:
//   V00sym : [2][32 wp][648 k]  (K=640 used; symmetric-folded, cell-pair enum)
//   V11sym : [2][32 wp][192 k]
//   V01t   : [2][256 row=(v*16+wp)][32 u]
//
//  R9 (R5 base = 535us; live-set capped to fit the immovable 128-reg budget):
//   - 5 attribute attempts (launch_bounds, waves_per_eu, num_vgpr, "+a")
//     never moved the allocator off 128 total unified regs; R8's AGPR pin
//     made it WORSE (AGPRs count against the same 128). So: fit honestly.
//   - conversion transient capped: {<=4 ds_read_b128 -> pkrtz} groups with
//     sched_barrier(0) fences (was: scheduler batched 20 reads = 80 regs).
//   - single accumulator (dual-acc's +16 persistent regs hurt: R7).
//   - plain stores (NT amplified WRITE_SIZE by ~90MB: R6/R7).
// ---------------------------------------------------------------------------

typedef __attribute__((ext_vector_type(8)))  _Float16 half8;
typedef __attribute__((ext_vector_type(2)))  _Float16 h16x2;
typedef __attribute__((ext_vector_type(16))) float    f32x16;
typedef __attribute__((ext_vector_type(4)))  float    f32x4;
typedef __attribute__((ext_vector_type(4)))  int      iv4;

#define V00_LDS_BYTES 82944              // 2*32*648*2
#define XBUF_BYTES    11264              // 704 chunks * 16B (32 rows * 84 f32 + pad)
#define SMEM_BYTES    (V00_LDS_BYTES + 7 * XBUF_BYTES)   // 161792 <= 163840
#define WS_V11_BYTE   82944
#define WS_V01_BYTE   107520
#define WAVE_STRIDE   1792               // 256 blocks * 7 waves

// ---- async global->LDS (16B per lane, linear dest = base + lane*16) --------
__device__ __forceinline__ void gll16(const void* g, void* l)
{
    __builtin_amdgcn_global_load_lds(
        (const __attribute__((address_space(1))) void*)g,
        (__attribute__((address_space(3))) void*)l,
        16, 0, 0);
}

#define WAIT_VM0()   asm volatile("s_waitcnt vmcnt(0)" ::: "memory")
#define WAIT_LGKM0() asm volatile("s_waitcnt lgkmcnt(0)" ::: "memory")
#define SCHED_FENCE() __builtin_amdgcn_sched_barrier(0)

// ---- packed f16 helpers ----------------------------------------------------
__device__ __forceinline__ unsigned pkrtz(float a, float b)
{
    auto h = __builtin_amdgcn_cvt_pkrtz(a, b);    // __fp16 ext_vector(2)
    unsigned u;
    __builtin_memcpy(&u, &h, 4);
    return u;
}
__device__ __forceinline__ unsigned pkmul(unsigned a, unsigned b)
{
    h16x2 r = __builtin_bit_cast(h16x2, a) * __builtin_bit_cast(h16x2, b);
    return __builtin_bit_cast(unsigned, r);
}
__device__ __forceinline__ unsigned pkfma(unsigned a, unsigned b, unsigned c)
{
    h16x2 r = __builtin_bit_cast(h16x2, a) * __builtin_bit_cast(h16x2, b)
            + __builtin_bit_cast(h16x2, c);       // -ffp-contract fuses
    return __builtin_bit_cast(unsigned, r);
}
// select low/high half per h1 and splat into both halves
__device__ __forceinline__ unsigned splat_sel(unsigned pair, int h1)
{
    unsigned v = h1 ? (pair >> 16) : (pair & 0xffffu);
    return v | (v << 16);
}
__device__ __forceinline__ float lo_f(unsigned p)
{
    return (float)__builtin_bit_cast(h16x2, p)[0];
}
__device__ __forceinline__ float hi_f(unsigned p)
{
    return (float)__builtin_bit_cast(h16x2, p)[1];
}

__device__ __forceinline__ f32x16 mfma_f16(iv4 a, iv4 b, f32x16 c)
{
    return __builtin_amdgcn_mfma_f32_32x32x16_f16(
        __builtin_bit_cast(half8, a), __builtin_bit_cast(half8, b), c, 0, 0, 0);
}

// ---- symmetric-pair cell enumeration (shared by prep + main) ---------------
// K-step kk -> (v-run r, base row u0); slot k = kk*16 + 8*h + j maps to the
// pair (u = u0 + h, v = 8*r + j); slots with v < u carry zero weight (pad).
__device__ __forceinline__ void dec00(int kk, int& r, int& u0)
{
    if      (kk < 4)  { r = 0; u0 = kk * 2; }
    else if (kk < 12) { r = 1; u0 = (kk - 4) * 2; }
    else if (kk < 24) { r = 2; u0 = (kk - 12) * 2; }
    else              { r = 3; u0 = (kk - 24) * 2; }
}
__device__ __forceinline__ void dec11(int kk, int& r, int& u0)
{
    if (kk < 4) { r = 0; u0 = kk * 2; }
    else        { r = 1; u0 = (kk - 4) * 2; }
}

// ---------------------------------------------------------------------------
// Precompute kernel: fold L0/L1 + path scales + symmetry into f16 weights.
// One thread per output element (70,144 total).
// ---------------------------------------------------------------------------
__global__ void prep_weights(const float* __restrict__ W00_1, const float* __restrict__ W01_1,
                             const float* __restrict__ W11_1, const float* __restrict__ W00_2,
                             const float* __restrict__ W01_2, const float* __restrict__ W11_2,
                             const float* __restrict__ L0,    const float* __restrict__ L1,
                             _Float16* __restrict__ ws)
{
    int t = blockIdx.x * 256 + threadIdx.x;
    const float s00 = 1.0f / (32.0f * sqrtf(32.0f));
    const float s11 = 0.57735026919f / (16.0f * sqrtf(32.0f));
    const float s01 = 1.0f / sqrtf(8192.0f);

    if (t < 2 * 32 * 648) {                       // V00sym
        int k  = t % 648;
        int rw = t / 648;
        int wp = rw & 31, s = rw >> 5;
        const float* W = s ? W00_2 : W00_1;
        float val = 0.f;
        int kk = k >> 4;
        if (kk < 40) {
            int h = (k >> 3) & 1, j = k & 7, r, u0;
            dec00(kk, r, u0);
            int u = u0 + h, v = 8 * r + j;
            if (v >= u) {
                float acc = 0.f;
                for (int w = 0; w < 32; ++w) {
                    float c = W[(u * 32 + v) * 32 + w];
                    if (u != v) c += W[(v * 32 + u) * 32 + w];
                    acc += c * L0[w * 32 + wp];
                }
                val = acc * s00;
            }
        }
        ws[t] = (_Float16)val;
        return;
    }
    t -= 2 * 32 * 648;
    if (t < 2 * 32 * 192) {                       // V11sym
        int k  = t % 192;
        int rw = t / 192;
        int wp = rw & 31, s = rw >> 5;
        const float* W = s ? W11_2 : W11_1;
        int kk = k >> 4, h = (k >> 3) & 1, j = k & 7, r, u0;
        dec11(kk, r, u0);
        int u = u0 + h, v = 8 * r + j;
        float val = 0.f;
        if (v >= u) {
            float acc = 0.f;
            for (int w = 0; w < 32; ++w) {
                float c = W[(u * 16 + v) * 32 + w];
                if (u != v) c += W[(v * 16 + u) * 32 + w];
                acc += c * L0[w * 32 + wp];
            }
            val = acc * s11;
        }
        ws[2 * 32 * 648 + t] = (_Float16)val;
        return;
    }
    t -= 2 * 32 * 192;
    if (t < 2 * 256 * 32) {                       // V01 (transposed, L1-folded)
        int u  = t & 31;
        int rw = t >> 5;
        int row = rw & 255, s = rw >> 8;
        int v = row >> 4, wp = row & 15;
        const float* W = s ? W01_2 : W01_1;
        float acc = 0.f;
        for (int w = 0; w < 16; ++w)
            acc += W[(u * 16 + v) * 16 + w] * L1[w * 16 + wp];
        ws[2 * 32 * 648 + 2 * 32 * 192 + t] = (_Float16)(acc * s01);
    }
}

// ---------------------------------------------------------------------------
// Stage one 32-node tile (80 f32/row) into LDS rows of stride 84 f32 (336B).
// 11 global_load_lds x 1KB; LDS dest linear, src index derived per lane.
// ---------------------------------------------------------------------------
__device__ __forceinline__ void stage32(const float* __restrict__ src, char* xbuf, int lane)
{
#pragma unroll
    for (int st = 0; st < 11; ++st) {
        int q  = st * 64 + lane;
        int r  = q / 21;
        int cc = q - r * 21;
        if (r > 31) { r = 31; cc = 20; }
        int col = cc * 4;
        if (col > 76) col = 76;                    // pad chunk -> dup last 16B
        gll16(src + r * 80 + col, xbuf + st * 1024);
    }
}

// ---------------------------------------------------------------------------
// Main kernel: 7 waves/block, 1 block/CU, each wave owns a 32-node tile loop.
// Live set deliberately capped to fit the 128-reg allocation (see header).
// ---------------------------------------------------------------------------
__global__ __launch_bounds__(448)
void tsq_main(const float* __restrict__ xf, const float* __restrict__ xm,
              const unsigned short* __restrict__ wsb, float* __restrict__ out,
              int ntiles)
{
    __shared__ __align__(16) char smem[SMEM_BYTES];
    const int lane = threadIdx.x & 63;
    const int wid  = (int)(threadIdx.x >> 6);
    const int h1   = lane >> 5;                    // lane-half
    const int wp   = lane & 31;
    char* xbuf = smem + V00_LDS_BYTES + wid * XBUF_BYTES;

    // ---- cooperative V00 load to LDS (81 KB-chunks) ----
    for (int c = wid; c < 81; c += 7)
        gll16((const char*)wsb + c * 1024 + lane * 16, smem + c * 1024);
    WAIT_VM0();
    __syncthreads();

    const int wg = blockIdx.x * 7 + wid;
    if (wg < ntiles)
        stage32(xf + (size_t)wg * 2560, xbuf, lane);

    for (int t = wg; t < ntiles; t += WAVE_STRIDE) {
        const int tn = t + WAVE_STRIDE;

        f32x16 acc0;
#pragma unroll
        for (int e = 0; e < 16; ++e) acc0[e] = 0.f;
        float z1a[8][3];
#pragma unroll
        for (int d = 0; d < 8; ++d) { z1a[d][0] = 0.f; z1a[d][1] = 0.f; z1a[d][2] = 0.f; }

#pragma unroll 1
        for (int s = 0; s < 2; ++s) {
            // staged x ready
            WAIT_VM0();

            // ---- read my node row, convert to packed f16 pairs ----
            // Grouped {<=4 ds_read_b128 -> pkrtz} with sched fences so the
            // scheduler cannot batch all 20 reads (80 transient regs).
            // xh0[q]    = (x0[2q], x0[2q+1])
            // xh1[i][p] = (x1[2p][i], x1[2p+1][i])
            unsigned xh0[16], xh1[3][8];
            const char* myrow = xbuf + wp * 336;
#pragma unroll
            for (int g = 0; g < 2; ++g) {
#pragma unroll
                for (int k = 4 * g; k < 4 * g + 4; ++k) {
                    float4 v = *reinterpret_cast<const float4*>(myrow + k * 16);
                    xh0[2 * k + 0] = pkrtz(v.x, v.y);
                    xh0[2 * k + 1] = pkrtz(v.z, v.w);
                }
                SCHED_FENCE();
            }
            // x1: rows v at float offset v*3+i; 3 float4s = 4 v-rows (2 pairs)
#pragma unroll
            for (int pp = 0; pp < 4; ++pp) {
                float4 a = *reinterpret_cast<const float4*>(myrow + 128 + pp * 48);
                float4 b = *reinterpret_cast<const float4*>(myrow + 128 + pp * 48 + 16);
                float4 c = *reinterpret_cast<const float4*>(myrow + 128 + pp * 48 + 32);
                xh1[0][2 * pp + 0] = pkrtz(a.x, a.w);   // rows 4pp,4pp+1  i=0
                xh1[1][2 * pp + 0] = pkrtz(a.y, b.x);   //                 i=1
                xh1[2][2 * pp + 0] = pkrtz(a.z, b.y);   //                 i=2
                xh1[0][2 * pp + 1] = pkrtz(b.z, c.y);   // rows 4pp+2,4pp+3
                xh1[1][2 * pp + 1] = pkrtz(b.w, c.z);
                xh1[2][2 * pp + 1] = pkrtz(c.x, c.w);
                SCHED_FENCE();
            }
            WAIT_LGKM0();                          // buffer reusable

            // ---- overlap: stage next piece while computing this one ----
            if (s == 0)            stage32(xm + (size_t)t  * 2560, xbuf, lane);
            else if (tn < ntiles)  stage32(xf + (size_t)tn * 2560, xbuf, lane);

            // ---- path 00 : z0 += V00sym x P00 (K=640) ----
            const char* v00b = smem + s * 41472 + wp * 1296 + h1 * 16;
#pragma unroll
            for (int kk = 0; kk < 40; ++kk) {
                int rr, u0; dec00(kk, rr, u0);
                unsigned ub = splat_sel(xh0[u0 >> 1], h1);   // CSE across kk
                iv4 bf;
#pragma unroll
                for (int q = 0; q < 4; ++q)
                    bf[q] = (int)pkmul(ub, xh0[4 * rr + q]);
                iv4 af = *reinterpret_cast<const iv4*>(v00b + kk * 32);
                acc0 = mfma_f16(af, bf, acc0);
            }

            // ---- path 11 : z0 += V11sym x D11 (K=192), weights from L2 ----
            const char* v11g = (const char*)wsb + WS_V11_BYTE
                             + (size_t)((s * 32 + wp) * 192) * 2 + h1 * 16;
#pragma unroll
            for (int kk = 0; kk < 12; ++kk) {
                int rr, u0; dec11(kk, rr, u0);
                int q0 = u0 >> 1;
                unsigned b0 = splat_sel(xh1[0][q0], h1);
                unsigned b1 = splat_sel(xh1[1][q0], h1);
                unsigned b2 = splat_sel(xh1[2][q0], h1);
                iv4 bf;
#pragma unroll
                for (int q = 0; q < 4; ++q) {
                    int vp = 4 * rr + q;
                    unsigned d = pkmul(b0, xh1[0][vp]);
                    d = pkfma(b1, xh1[1][vp], d);
                    d = pkfma(b2, xh1[2][vp], d);
                    bf[q] = (int)d;
                }
                iv4 af = *reinterpret_cast<const iv4*>(v11g + kk * 32);
                acc0 = mfma_f16(af, bf, acc0);
            }

            // ---- path 01 : t = V01t x x0 (K=32), then VALU contract over v ----
            iv4 b01[2];
#pragma unroll
            for (int kk = 0; kk < 2; ++kk)
#pragma unroll
                for (int q = 0; q < 4; ++q)
                    b01[kk][q] = (int)xh0[kk * 8 + 4 * h1 + q];

            const char* v01g = (const char*)wsb + WS_V01_BYTE
                             + (size_t)((s * 256 + wp) * 32) * 2 + h1 * 16;
#pragma unroll
            for (int m = 0; m < 8; ++m) {
                iv4 a0 = *reinterpret_cast<const iv4*>(v01g + m * 2048);
                iv4 a1 = *reinterpret_cast<const iv4*>(v01g + m * 2048 + 32);
                f32x16 tq;
#pragma unroll
                for (int e = 0; e < 16; ++e) tq[e] = 0.f;
                tq = mfma_f16(a0, b01[0], tq);
                tq = mfma_f16(a1, b01[1], tq);
                float x1f[2][3];
#pragma unroll
                for (int i = 0; i < 3; ++i) {
                    unsigned p = xh1[i][m];
                    x1f[0][i] = lo_f(p);           // v = 2m
                    x1f[1][i] = hi_f(p);           // v = 2m+1
                }
#pragma unroll
                for (int reg = 0; reg < 16; ++reg) {
                    int vloc = reg >> 3;
                    int d    = (reg & 3) + 4 * ((reg >> 2) & 1);
                    z1a[d][0] = fmaf(tq[reg], x1f[vloc][0], z1a[d][0]);
                    z1a[d][1] = fmaf(tq[reg], x1f[vloc][1], z1a[d][1]);
                    z1a[d][2] = fmaf(tq[reg], x1f[vloc][2], z1a[d][2]);
                }
            }
        } // set loop

        // ---- epilogue: this lane owns node (t*32 + wp), half-split outputs ----
        float* orow = out + (size_t)(t * 32 + wp) * 80;
#pragma unroll
        for (int qn = 0; qn < 4; ++qn) {
            f32x4 vz = { acc0[4 * qn + 0], acc0[4 * qn + 1],
                         acc0[4 * qn + 2], acc0[4 * qn + 3] };
            *reinterpret_cast<f32x4*>(orow + 8 * qn + 4 * h1) = vz;
        }
        float* p1 = orow + 32 + 12 * h1;
        {
            f32x4 a = { z1a[0][0], z1a[0][1], z1a[0][2], z1a[1][0] };
            f32x4 b = { z1a[1][1], z1a[1][2], z1a[2][0], z1a[2][1] };
            f32x4 c = { z1a[2][2], z1a[3][0], z1a[3][1], z1a[3][2] };
            *reinterpret_cast<f32x4*>(p1 + 0) = a;
            *reinterpret_cast<f32x4*>(p1 + 4) = b;
            *reinterpret_cast<f32x4*>(p1 + 8) = c;
        }
        float* p2 = orow + 56 + 12 * h1;
        {
            f32x4 a = { z1a[4][0], z1a[4][1], z1a[4][2], z1a[5][0] };
            f32x4 b = { z1a[5][1], z1a[5][2], z1a[6][0], z1a[6][1] };
            f32x4 c = { z1a[6][2], z1a[7][0], z1a[7][1], z1a[7][2] };
            *reinterpret_cast<f32x4*>(p2 + 0) = a;
            *reinterpret_cast<f32x4*>(p2 + 4) = b;
            *reinterpret_cast<f32x4*>(p2 + 8) = c;
        }
    }
}

// ---------------------------------------------------------------------------
extern "C" void kernel_launch(void* const* d_in, const int* in_sizes, int n_in,
                              void* d_out, int out_size, void* d_ws, size_t ws_size,
                              hipStream_t stream)
{
    const float* xf    = (const float*)d_in[0];
    const float* xm    = (const float*)d_in[1];
    const float* W00_1 = (const float*)d_in[2];
    const float* W01_1 = (const float*)d_in[3];
    const float* W11_1 = (const float*)d_in[4];
    const float* W00_2 = (const float*)d_in[5];
    const float* W01_2 = (const float*)d_in[6];
    const float* W11_2 = (const float*)d_in[7];
    const float* L0    = (const float*)d_in[8];
    const float* L1    = (const float*)d_in[9];

    const int N      = in_sizes[0] / 80;           // 1,000,000
    const int ntiles = N / 32;                     // 31,250 (exact)

    prep_weights<<<274, 256, 0, stream>>>(W00_1, W01_1, W11_1,
                                          W00_2, W01_2, W11_2,
                                          L0, L1, (_Float16*)d_ws);

    tsq_main<<<256, 448, 0, stream>>>(xf, xm,
                                      (const unsigned short*)d_ws,
                                      (float*)d_out, ntiles);
}

// Round 10
// 447.460 us; speedup vs baseline: 1.6369x; 1.1627x over previous
//
#include <hip/hip_runtime.h>
#include <hip/hip_bf16.h>

// ---------------------------------------------------------------------------
// SeparateTSQLinearNodeBlock: fused weighted symmetric TensorSquare (x2) +
// equivariant Linear, fp16 MFMA formulation.
//
//  out[n, 0:32]        = z0  = sum over paths (00, 11) x (feats, messages)
//  out[n, 32 + 3w + i] = z1  = path 01 x (feats, messages)
//
//  All CG/path/linear scales folded into precomputed f16 weights in d_ws:
//   V00sym : [2][32 wp][648 k]  (K=640 used; symmetric-folded, cell-pair enum)
//   V11sym : [2][32 wp][192 k]
//   V01t   : [2][256 row=(v*16+wp)][32 u]
//
//  R10 (R9 = 520us + fences extended into the path loops):
//   - the pre-RA scheduler batches the unrolled loops' loads (path00 can
//     hoist 40x4=160 regs of ds_reads) -> spill spikes under the immovable
//     128-reg budget (R9 residual: WRITE 481MB vs 320 ideal).
//   - sched_barrier(0) every 2 iters (path00/path11), every iter (path01),
//     + one fence pinning stage32's issue point.
// ---------------------------------------------------------------------------

typedef __attribute__((ext_vector_type(8)))  _Float16 half8;
typedef __attribute__((ext_vector_type(2)))  _Float16 h16x2;
typedef __attribute__((ext_vector_type(16))) float    f32x16;
typedef __attribute__((ext_vector_type(4)))  float    f32x4;
typedef __attribute__((ext_vector_type(4)))  int      iv4;

#define V00_LDS_BYTES 82944              // 2*32*648*2
#define XBUF_BYTES    11264              // 704 chunks * 16B (32 rows * 84 f32 + pad)
#define SMEM_BYTES    (V00_LDS_BYTES + 7 * XBUF_BYTES)   // 161792 <= 163840
#define WS_V11_BYTE   82944
#define WS_V01_BYTE   107520
#define WAVE_STRIDE   1792               // 256 blocks * 7 waves

// ---- async global->LDS (16B per lane, linear dest = base + lane*16) --------
__device__ __forceinline__ void gll16(const void* g, void* l)
{
    __builtin_amdgcn_global_load_lds(
        (const __attribute__((address_space(1))) void*)g,
        (__attribute__((address_space(3))) void*)l,
        16, 0, 0);
}

#define WAIT_VM0()   asm volatile("s_waitcnt vmcnt(0)" ::: "memory")
#define WAIT_LGKM0() asm volatile("s_waitcnt lgkmcnt(0)" ::: "memory")
#define SCHED_FENCE() __builtin_amdgcn_sched_barrier(0)

// ---- packed f16 helpers ----------------------------------------------------
__device__ __forceinline__ unsigned pkrtz(float a, float b)
{
    auto h = __builtin_amdgcn_cvt_pkrtz(a, b);    // __fp16 ext_vector(2)
    unsigned u;
    __builtin_memcpy(&u, &h, 4);
    return u;
}
__device__ __forceinline__ unsigned pkmul(unsigned a, unsigned b)
{
    h16x2 r = __builtin_bit_cast(h16x2, a) * __builtin_bit_cast(h16x2, b);
    return __builtin_bit_cast(unsigned, r);
}
__device__ __forceinline__ unsigned pkfma(unsigned a, unsigned b, unsigned c)
{
    h16x2 r = __builtin_bit_cast(h16x2, a) * __builtin_bit_cast(h16x2, b)
            + __builtin_bit_cast(h16x2, c);       // -ffp-contract fuses
    return __builtin_bit_cast(unsigned, r);
}
// select low/high half per h1 and splat into both halves
__device__ __forceinline__ unsigned splat_sel(unsigned pair, int h1)
{
    unsigned v = h1 ? (pair >> 16) : (pair & 0xffffu);
    return v | (v << 16);
}
__device__ __forceinline__ float lo_f(unsigned p)
{
    return (float)__builtin_bit_cast(h16x2, p)[0];
}
__device__ __forceinline__ float hi_f(unsigned p)
{
    return (float)__builtin_bit_cast(h16x2, p)[1];
}

__device__ __forceinline__ f32x16 mfma_f16(iv4 a, iv4 b, f32x16 c)
{
    return __builtin_amdgcn_mfma_f32_32x32x16_f16(
        __builtin_bit_cast(half8, a), __builtin_bit_cast(half8, b), c, 0, 0, 0);
}

// ---- symmetric-pair cell enumeration (shared by prep + main) ---------------
// K-step kk -> (v-run r, base row u0); slot k = kk*16 + 8*h + j maps to the
// pair (u = u0 + h, v = 8*r + j); slots with v < u carry zero weight (pad).
__device__ __forceinline__ void dec00(int kk, int& r, int& u0)
{
    if      (kk < 4)  { r = 0; u0 = kk * 2; }
    else if (kk < 12) { r = 1; u0 = (kk - 4) * 2; }
    else if (kk < 24) { r = 2; u0 = (kk - 12) * 2; }
    else              { r = 3; u0 = (kk - 24) * 2; }
}
__device__ __forceinline__ void dec11(int kk, int& r, int& u0)
{
    if (kk < 4) { r = 0; u0 = kk * 2; }
    else        { r = 1; u0 = (kk - 4) * 2; }
}

// ---------------------------------------------------------------------------
// Precompute kernel: fold L0/L1 + path scales + symmetry into f16 weights.
// One thread per output element (70,144 total).
// ---------------------------------------------------------------------------
__global__ void prep_weights(const float* __restrict__ W00_1, const float* __restrict__ W01_1,
                             const float* __restrict__ W11_1, const float* __restrict__ W00_2,
                             const float* __restrict__ W01_2, const float* __restrict__ W11_2,
                             const float* __restrict__ L0,    const float* __restrict__ L1,
                             _Float16* __restrict__ ws)
{
    int t = blockIdx.x * 256 + threadIdx.x;
    const float s00 = 1.0f / (32.0f * sqrtf(32.0f));
    const float s11 = 0.57735026919f / (16.0f * sqrtf(32.0f));
    const float s01 = 1.0f / sqrtf(8192.0f);

    if (t < 2 * 32 * 648) {                       // V00sym
        int k  = t % 648;
        int rw = t / 648;
        int wp = rw & 31, s = rw >> 5;
        const float* W = s ? W00_2 : W00_1;
        float val = 0.f;
        int kk = k >> 4;
        if (kk < 40) {
            int h = (k >> 3) & 1, j = k & 7, r, u0;
            dec00(kk, r, u0);
            int u = u0 + h, v = 8 * r + j;
            if (v >= u) {
                float acc = 0.f;
                for (int w = 0; w < 32; ++w) {
                    float c = W[(u * 32 + v) * 32 + w];
                    if (u != v) c += W[(v * 32 + u) * 32 + w];
                    acc += c * L0[w * 32 + wp];
                }
                val = acc * s00;
            }
        }
        ws[t] = (_Float16)val;
        return;
    }
    t -= 2 * 32 * 648;
    if (t < 2 * 32 * 192) {                       // V11sym
        int k  = t % 192;
        int rw = t / 192;
        int wp = rw & 31, s = rw >> 5;
        const float* W = s ? W11_2 : W11_1;
        int kk = k >> 4, h = (k >> 3) & 1, j = k & 7, r, u0;
        dec11(kk, r, u0);
        int u = u0 + h, v = 8 * r + j;
        float val = 0.f;
        if (v >= u) {
            float acc = 0.f;
            for (int w = 0; w < 32; ++w) {
                float c = W[(u * 16 + v) * 32 + w];
                if (u != v) c += W[(v * 16 + u) * 32 + w];
                acc += c * L0[w * 32 + wp];
            }
            val = acc * s11;
        }
        ws[2 * 32 * 648 + t] = (_Float16)val;
        return;
    }
    t -= 2 * 32 * 192;
    if (t < 2 * 256 * 32) {                       // V01 (transposed, L1-folded)
        int u  = t & 31;
        int rw = t >> 5;
        int row = rw & 255, s = rw >> 8;
        int v = row >> 4, wp = row & 15;
        const float* W = s ? W01_2 : W01_1;
        float acc = 0.f;
        for (int w = 0; w < 16; ++w)
            acc += W[(u * 16 + v) * 16 + w] * L1[w * 16 + wp];
        ws[2 * 32 * 648 + 2 * 32 * 192 + t] = (_Float16)(acc * s01);
    }
}

// ---------------------------------------------------------------------------
// Stage one 32-node tile (80 f32/row) into LDS rows of stride 84 f32 (336B).
// 11 global_load_lds x 1KB; LDS dest linear, src index derived per lane.
// ---------------------------------------------------------------------------
__device__ __forceinline__ void stage32(const float* __restrict__ src, char* xbuf, int lane)
{
#pragma unroll
    for (int st = 0; st < 11; ++st) {
        int q  = st * 64 + lane;
        int r  = q / 21;
        int cc = q - r * 21;
        if (r > 31) { r = 31; cc = 20; }
        int col = cc * 4;
        if (col > 76) col = 76;                    // pad chunk -> dup last 16B
        gll16(src + r * 80 + col, xbuf + st * 1024);
    }
}

// ---------------------------------------------------------------------------
// Main kernel: 7 waves/block, 1 block/CU, each wave owns a 32-node tile loop.
// Live set deliberately capped to fit the 128-reg allocation; sched fences
// keep the scheduler from batching loads into register spikes.
// ---------------------------------------------------------------------------
__global__ __launch_bounds__(448)
void tsq_main(const float* __restrict__ xf, const float* __restrict__ xm,
              const unsigned short* __restrict__ wsb, float* __restrict__ out,
              int ntiles)
{
    __shared__ __align__(16) char smem[SMEM_BYTES];
    const int lane = threadIdx.x & 63;
    const int wid  = (int)(threadIdx.x >> 6);
    const int h1   = lane >> 5;                    // lane-half
    const int wp   = lane & 31;
    char* xbuf = smem + V00_LDS_BYTES + wid * XBUF_BYTES;

    // ---- cooperative V00 load to LDS (81 KB-chunks) ----
    for (int c = wid; c < 81; c += 7)
        gll16((const char*)wsb + c * 1024 + lane * 16, smem + c * 1024);
    WAIT_VM0();
    __syncthreads();

    const int wg = blockIdx.x * 7 + wid;
    if (wg < ntiles)
        stage32(xf + (size_t)wg * 2560, xbuf, lane);

    for (int t = wg; t < ntiles; t += WAVE_STRIDE) {
        const int tn = t + WAVE_STRIDE;

        f32x16 acc0;
#pragma unroll
        for (int e = 0; e < 16; ++e) acc0[e] = 0.f;
        float z1a[8][3];
#pragma unroll
        for (int d = 0; d < 8; ++d) { z1a[d][0] = 0.f; z1a[d][1] = 0.f; z1a[d][2] = 0.f; }

#pragma unroll 1
        for (int s = 0; s < 2; ++s) {
            // staged x ready
            WAIT_VM0();

            // ---- read my node row, convert to packed f16 pairs ----
            // Grouped {<=4 ds_read_b128 -> pkrtz} with sched fences so the
            // scheduler cannot batch all 20 reads (80 transient regs).
            // xh0[q]    = (x0[2q], x0[2q+1])
            // xh1[i][p] = (x1[2p][i], x1[2p+1][i])
            unsigned xh0[16], xh1[3][8];
            const char* myrow = xbuf + wp * 336;
#pragma unroll
            for (int g = 0; g < 2; ++g) {
#pragma unroll
                for (int k = 4 * g; k < 4 * g + 4; ++k) {
                    float4 v = *reinterpret_cast<const float4*>(myrow + k * 16);
                    xh0[2 * k + 0] = pkrtz(v.x, v.y);
                    xh0[2 * k + 1] = pkrtz(v.z, v.w);
                }
                SCHED_FENCE();
            }
            // x1: rows v at float offset v*3+i; 3 float4s = 4 v-rows (2 pairs)
#pragma unroll
            for (int pp = 0; pp < 4; ++pp) {
                float4 a = *reinterpret_cast<const float4*>(myrow + 128 + pp * 48);
                float4 b = *reinterpret_cast<const float4*>(myrow + 128 + pp * 48 + 16);
                float4 c = *reinterpret_cast<const float4*>(myrow + 128 + pp * 48 + 32);
                xh1[0][2 * pp + 0] = pkrtz(a.x, a.w);   // rows 4pp,4pp+1  i=0
                xh1[1][2 * pp + 0] = pkrtz(a.y, b.x);   //                 i=1
                xh1[2][2 * pp + 0] = pkrtz(a.z, b.y);   //                 i=2
                xh1[0][2 * pp + 1] = pkrtz(b.z, c.y);   // rows 4pp+2,4pp+3
                xh1[1][2 * pp + 1] = pkrtz(b.w, c.z);
                xh1[2][2 * pp + 1] = pkrtz(c.x, c.w);
                SCHED_FENCE();
            }
            WAIT_LGKM0();                          // buffer reusable

            // ---- overlap: stage next piece while computing this one ----
            if (s == 0)            stage32(xm + (size_t)t  * 2560, xbuf, lane);
            else if (tn < ntiles)  stage32(xf + (size_t)tn * 2560, xbuf, lane);
            SCHED_FENCE();                         // pin staging issue point

            // ---- path 00 : z0 += V00sym x P00 (K=640) ----
            const char* v00b = smem + s * 41472 + wp * 1296 + h1 * 16;
#pragma unroll
            for (int kk = 0; kk < 40; ++kk) {
                int rr, u0; dec00(kk, rr, u0);
                unsigned ub = splat_sel(xh0[u0 >> 1], h1);   // CSE across kk
                iv4 bf;
#pragma unroll
                for (int q = 0; q < 4; ++q)
                    bf[q] = (int)pkmul(ub, xh0[4 * rr + q]);
                iv4 af = *reinterpret_cast<const iv4*>(v00b + kk * 32);
                acc0 = mfma_f16(af, bf, acc0);
                if (kk & 1) SCHED_FENCE();         // cap ds_read batching
            }

            // ---- path 11 : z0 += V11sym x D11 (K=192), weights from L2 ----
            const char* v11g = (const char*)wsb + WS_V11_BYTE
                             + (size_t)((s * 32 + wp) * 192) * 2 + h1 * 16;
#pragma unroll
            for (int kk = 0; kk < 12; ++kk) {
                int rr, u0; dec11(kk, rr, u0);
                int q0 = u0 >> 1;
                unsigned b0 = splat_sel(xh1[0][q0], h1);
                unsigned b1 = splat_sel(xh1[1][q0], h1);
                unsigned b2 = splat_sel(xh1[2][q0], h1);
                iv4 bf;
#pragma unroll
                for (int q = 0; q < 4; ++q) {
                    int vp = 4 * rr + q;
                    unsigned d = pkmul(b0, xh1[0][vp]);
                    d = pkfma(b1, xh1[1][vp], d);
                    d = pkfma(b2, xh1[2][vp], d);
                    bf[q] = (int)d;
                }
                iv4 af = *reinterpret_cast<const iv4*>(v11g + kk * 32);
                acc0 = mfma_f16(af, bf, acc0);
                if (kk & 1) SCHED_FENCE();         // cap L2-load batching
            }

            // ---- path 01 : t = V01t x x0 (K=32), then VALU contract over v ----
            iv4 b01[2];
#pragma unroll
            for (int kk = 0; kk < 2; ++kk)
#pragma unroll
                for (int q = 0; q < 4; ++q)
                    b01[kk][q] = (int)xh0[kk * 8 + 4 * h1 + q];

            const char* v01g = (const char*)wsb + WS_V01_BYTE
                             + (size_t)((s * 256 + wp) * 32) * 2 + h1 * 16;
#pragma unroll
            for (int m = 0; m < 8; ++m) {
                iv4 a0 = *reinterpret_cast<const iv4*>(v01g + m * 2048);
                iv4 a1 = *reinterpret_cast<const iv4*>(v01g + m * 2048 + 32);
                f32x16 tq;
#pragma unroll
                for (int e = 0; e < 16; ++e) tq[e] = 0.f;
                tq = mfma_f16(a0, b01[0], tq);
                tq = mfma_f16(a1, b01[1], tq);
                float x1f[2][3];
#pragma unroll
                for (int i = 0; i < 3; ++i) {
                    unsigned p = xh1[i][m];
                    x1f[0][i] = lo_f(p);           // v = 2m
                    x1f[1][i] = hi_f(p);           // v = 2m+1
                }
#pragma unroll
                for (int reg = 0; reg < 16; ++reg) {
                    int vloc = reg >> 3;
                    int d    = (reg & 3) + 4 * ((reg >> 2) & 1);
                    z1a[d][0] = fmaf(tq[reg], x1f[vloc][0], z1a[d][0]);
                    z1a[d][1] = fmaf(tq[reg], x1f[vloc][1], z1a[d][1]);
                    z1a[d][2] = fmaf(tq[reg], x1f[vloc][2], z1a[d][2]);
                }
                SCHED_FENCE();                     // cap tq/a0/a1 batching
            }
        } // set loop

        // ---- epilogue: this lane owns node (t*32 + wp), half-split outputs ----
        float* orow = out + (size_t)(t * 32 + wp) * 80;
#pragma unroll
        for (int qn = 0; qn < 4; ++qn) {
            f32x4 vz = { acc0[4 * qn + 0], acc0[4 * qn + 1],
                         acc0[4 * qn + 2], acc0[4 * qn + 3] };
            *reinterpret_cast<f32x4*>(orow + 8 * qn + 4 * h1) = vz;
        }
        float* p1 = orow + 32 + 12 * h1;
        {
            f32x4 a = { z1a[0][0], z1a[0][1], z1a[0][2], z1a[1][0] };
            f32x4 b = { z1a[1][1], z1a[1][2], z1a[2][0], z1a[2][1] };
            f32x4 c = { z1a[2][2], z1a[3][0], z1a[3][1], z1a[3][2] };
            *reinterpret_cast<f32x4*>(p1 + 0) = a;
            *reinterpret_cast<f32x4*>(p1 + 4) = b;
            *reinterpret_cast<f32x4*>(p1 + 8) = c;
        }
        float* p2 = orow + 56 + 12 * h1;
        {
            f32x4 a = { z1a[4][0], z1a[4][1], z1a[4][2], z1a[5][0] };
            f32x4 b = { z1a[5][1], z1a[5][2], z1a[6][0], z1a[6][1] };
            f32x4 c = { z1a[6][2], z1a[7][0], z1a[7][1], z1a[7][2] };
            *reinterpret_cast<f32x4*>(p2 + 0) = a;
            *reinterpret_cast<f32x4*>(p2 + 4) = b;
            *reinterpret_cast<f32x4*>(p2 + 8) = c;
        }
    }
}

// ---------------------------------------------------------------------------
extern "C" void kernel_launch(void* const* d_in, const int* in_sizes, int n_in,
                              void* d_out, int out_size, void* d_ws, size_t ws_size,
                              hipStream_t stream)
{
    const float* xf    = (const float*)d_in[0];
    const float* xm    = (const float*)d_in[1];
    const float* W00_1 = (const float*)d_in[2];
    const float* W01_1 = (const float*)d_in[3];
    const float* W11_1 = (const float*)d_in[4];
    const float* W00_2 = (const float*)d_in[5];
    const float* W01_2 = (const float*)d_in[6];
    const float* W11_2 = (const float*)d_in[7];
    const float* L0    = (const float*)d_in[8];
    const float* L1    = (const float*)d_in[9];

    const int N      = in_sizes[0] / 80;           // 1,000,000
    const int ntiles = N / 32;                     // 31,250 (exact)

    prep_weights<<<274, 256, 0, stream>>>(W00_1, W01_1, W11_1,
                                          W00_2, W01_2, W11_2,
                                          L0, L1, (_Float16*)d_ws);

    tsq_main<<<256, 448, 0, stream>>>(xf, xm,
                                      (const unsigned short*)d_ws,
                                      (float*)d_out, ntiles);
}